// Round 1
// baseline (639.772 us; speedup 1.0000x reference)
//
#include <hip/hip_runtime.h>

#define NB    65536   // batch rows
#define DIN   768     // hidden dim
#define DCB   192     // codebook hidden
#define KCL   100     // clusters
#define NJ    112     // padded j (100 scores + col100=mu + pad)
#define RT    64      // rows per block (main kernel)
#define KC    64      // k-chunk

// workspace layout (float offsets)
#define OFF_KTIL 0        // 100*192
#define OFF_S    19200    // 100*192
#define OFF_CS   38400    // 112
#define OFF_U    38512    // 112
#define OFF_T    38624    // 112
#define OFF_MT   38736    // 112*768
#define OFF_ZH   124752   // 100*768
#define OFF_FLAG 201552   // 1 int

// ---------------- setup kernels (tiny, f64 accumulation) ----------------

// ktil[j][i] = sum_m cb[j,m]*Wk[i,m];  also init flag=0
__global__ void kA1(const float* __restrict__ cb, const float* __restrict__ Wk,
                    float* __restrict__ ktil, int* __restrict__ flag) {
  int j = blockIdx.x, i = threadIdx.x;  // block=192
  if (j == 0 && i == 0) *flag = 0;
  double s = 0.0;
  for (int m = 0; m < DCB; m++) s += (double)cb[j*DCB+m] * (double)Wk[i*DCB+m];
  ktil[j*DCB+i] = (float)s;
}

// A[j,c] = sum_i Wq[i,c]*ktil[j,i];  S=ln_g*A;  csum[j]=sum_c S;  t[j]=sum_c ln_b*A;
// u[j]=sum_c b_low*S;  u[100]=sum(b_low)/192; pads. flag|=any t!=0.
__global__ void kA2(const float* __restrict__ Wq, const float* __restrict__ ktil,
                    const float* __restrict__ ln_g, const float* __restrict__ ln_b,
                    const float* __restrict__ b_low,
                    float* __restrict__ S, float* __restrict__ csum,
                    float* __restrict__ tv, float* __restrict__ u,
                    int* __restrict__ flag) {
  __shared__ double red[DCB];
  int j = blockIdx.x, c = threadIdx.x;  // block=192
  double a = 0.0;
  for (int i = 0; i < DCB; i++) a += (double)Wq[i*DCB+c] * (double)ktil[j*DCB+i];
  float Sv = ln_g[c] * (float)a;
  S[j*DCB+c] = Sv;
  red[c] = (double)Sv; __syncthreads();
  if (c == 0) { double s = 0; for (int i = 0; i < DCB; i++) s += red[i]; csum[j] = (float)s; }
  __syncthreads();
  red[c] = (double)ln_b[c] * a; __syncthreads();
  if (c == 0) {
    double s = 0; for (int i = 0; i < DCB; i++) s += red[i];
    float tf = (float)s; tv[j] = tf;
    if (tf != 0.0f) atomicOr(flag, 1);
  }
  __syncthreads();
  red[c] = (double)b_low[c] * (double)Sv; __syncthreads();
  if (c == 0) { double s = 0; for (int i = 0; i < DCB; i++) s += red[i]; u[j] = (float)s; }
  __syncthreads();
  if (j == 0) {
    red[c] = (double)b_low[c]; __syncthreads();
    if (c == 0) {
      double s = 0; for (int i = 0; i < DCB; i++) s += red[i];
      u[KCL] = (float)(s / (double)DCB);
      for (int p = KCL+1; p < NJ; p++) u[p] = 0.f;
      for (int p = KCL;   p < NJ; p++) { csum[p] = 0.f; tv[p] = 0.f; }
    }
  }
}

// Mt[j][d] = sum_c W_low[c,d]*S[j,c]; row 100 = colmean of W_low; pads = 0
__global__ void kA3(const float* __restrict__ W_low, const float* __restrict__ S,
                    float* __restrict__ Mt) {
  int d = blockIdx.x, j = threadIdx.x;  // grid=768, block=128
  if (j < KCL) {
    double s = 0.0;
    for (int c = 0; c < DCB; c++) s += (double)W_low[c*DIN+d] * (double)S[j*DCB+c];
    Mt[(size_t)j*DIN + d] = (float)s;
  } else if (j == KCL) {
    double s = 0.0;
    for (int c = 0; c < DCB; c++) s += (double)W_low[c*DIN+d];
    Mt[(size_t)KCL*DIN + d] = (float)(s / (double)DCB);
  } else if (j < NJ) {
    Mt[(size_t)j*DIN + d] = 0.f;
  }
}

// ZH[j][d] = sum_c cb[j,c]*W_high[d,c] + b_high[d]
__global__ void kA4(const float* __restrict__ cb, const float* __restrict__ W_high,
                    const float* __restrict__ b_high, float* __restrict__ ZH) {
  int j = blockIdx.x;  // block=256
  for (int d = threadIdx.x; d < DIN; d += 256) {
    double s = 0.0;
    for (int c = 0; c < DCB; c++) s += (double)cb[j*DCB+c] * (double)W_high[d*DCB+c];
    ZH[(size_t)j*DIN + d] = (float)(s + (double)b_high[d]);
  }
}

// ---------------- main kernel ----------------
__global__ __launch_bounds__(256, 2)
void kB(const float* __restrict__ hidden, float* __restrict__ out,
        const float* __restrict__ Mt, const float* __restrict__ u,
        const float* __restrict__ csum, const float* __restrict__ ZH,
        const int* __restrict__ flag,
        const float* __restrict__ S, const float* __restrict__ tv,
        const float* __restrict__ W_low, const float* __restrict__ b_low) {
  __shared__ float hs[RT * 68];    // 64 rows x 64 k, stride 68
  __shared__ float Ms[NJ * 68];    // 112 j  x 64 k, stride 68
  __shared__ float Gs[RT * 113];   // 64 rows x 112 j, stride 113 (odd -> conflict-free)
  __shared__ int   idxs[RT];
  const int tid = threadIdx.x;
  const int r0  = blockIdx.x * RT;

  if (*flag == 0) {
    // ---- fast path: ln_b == 0 so t == 0 and argmax is invariant to the LN scale r ----
    const int jg = tid & 15, rg = tid >> 4;
    const int jbase = jg * 7, rbase = rg * 4;
    float acc[4][7];
    #pragma unroll
    for (int i = 0; i < 4; i++)
      #pragma unroll
      for (int j = 0; j < 7; j++) acc[i][j] = 0.f;

    for (int ck = 0; ck < DIN / KC; ck++) {
      const int k0 = ck * KC;
      __syncthreads();
      #pragma unroll
      for (int i = 0; i < 4; i++) {            // hidden tile: 1024 float4
        int f = tid + 256 * i;
        int r = f >> 4, k4 = f & 15;
        float4 v = *(const float4*)&hidden[(size_t)(r0 + r) * DIN + k0 + k4 * 4];
        *(float4*)&hs[r * 68 + k4 * 4] = v;
      }
      #pragma unroll
      for (int i = 0; i < 7; i++) {            // Mt tile: 1792 float4
        int f = tid + 256 * i;
        int j = f >> 4, k4 = f & 15;
        float4 v = *(const float4*)&Mt[(size_t)j * DIN + k0 + k4 * 4];
        *(float4*)&Ms[j * 68 + k4 * 4] = v;
      }
      __syncthreads();
      #pragma unroll
      for (int kk = 0; kk < KC; kk += 4) {
        float4 h4[4], m4[7];
        #pragma unroll
        for (int i = 0; i < 4; i++) h4[i] = *(const float4*)&hs[(rbase + i) * 68 + kk];
        #pragma unroll
        for (int j = 0; j < 7; j++) m4[j] = *(const float4*)&Ms[(jbase + j) * 68 + kk];
        #pragma unroll
        for (int i = 0; i < 4; i++)
          #pragma unroll
          for (int j = 0; j < 7; j++) {
            acc[i][j] += h4[i].x * m4[j].x;
            acc[i][j] += h4[i].y * m4[j].y;
            acc[i][j] += h4[i].z * m4[j].z;
            acc[i][j] += h4[i].w * m4[j].w;
          }
      }
    }
    __syncthreads();
    #pragma unroll
    for (int i = 0; i < 4; i++)
      #pragma unroll
      for (int j = 0; j < 7; j++)
        Gs[(rbase + i) * 113 + jbase + j] = acc[i][j] + u[jbase + j];
    __syncthreads();
    if (tid < RT) {
      const int r = tid;
      const float mu = Gs[r * 113 + KCL];
      float best = -3.4e38f; int bi = 0;
      for (int j = 0; j < KCL; j++) {
        float s = Gs[r * 113 + j] - mu * csum[j];
        if (s > best) { best = s; bi = j; }   // strict > : first max == np first min of attn_w
      }
      idxs[r] = bi;
    }
    __syncthreads();
    for (int i = 0; i < 48; i++) {            // copy ZH[idx] rows: 12288 float4
      int f = tid + 256 * i;
      int r = f / 192, d4 = f - r * 192;
      int idx = idxs[r];
      float4 v = *(const float4*)&ZH[(size_t)idx * DIN + d4 * 4];
      *(float4*)&out[(size_t)(r0 + r) * DIN + d4 * 4] = v;
    }
  } else {
    // ---- general (slow) path: ln_b != 0 -> need full pat + LayerNorm. Correctness only. ----
    float* hrow = hs;          // 768
    float* patv = hs + 768;    // 192
    float* redf = hs + 960;    // 2
    for (int rr = 0; rr < RT; rr++) {
      const size_t row = (size_t)(r0 + rr);
      __syncthreads();
      for (int d = tid; d < DIN; d += 256) hrow[d] = hidden[row * DIN + d];
      __syncthreads();
      if (tid < DCB) {
        float a = b_low[tid];
        for (int d = 0; d < DIN; d++) a += hrow[d] * W_low[(size_t)tid * DIN + d];
        patv[tid] = a;
      }
      __syncthreads();
      if (tid == 0) {
        float mu = 0.f; for (int c = 0; c < DCB; c++) mu += patv[c]; mu /= (float)DCB;
        float var = 0.f; for (int c = 0; c < DCB; c++) { float dd = patv[c] - mu; var += dd * dd; }
        var /= (float)DCB;
        redf[0] = mu; redf[1] = rsqrtf(var + 1e-5f);
      }
      __syncthreads();
      if (tid < DCB) patv[tid] = (patv[tid] - redf[0]) * redf[1];
      __syncthreads();
      if (tid < KCL) {
        float s = tv[tid];
        for (int c = 0; c < DCB; c++) s += patv[c] * S[(size_t)tid * DCB + c];
        Gs[tid] = s;
      }
      __syncthreads();
      if (tid == 0) {
        float best = -3.4e38f; int bi = 0;
        for (int j = 0; j < KCL; j++) if (Gs[j] > best) { best = Gs[j]; bi = j; }
        idxs[0] = bi;
      }
      __syncthreads();
      {
        int idx = idxs[0];
        for (int d4 = tid; d4 < DIN / 4; d4 += 256) {
          float4 v = *(const float4*)&ZH[(size_t)idx * DIN + d4 * 4];
          *(float4*)&out[row * DIN + d4 * 4] = v;
        }
      }
    }
  }
}

extern "C" void kernel_launch(void* const* d_in, const int* in_sizes, int n_in,
                              void* d_out, int out_size, void* d_ws, size_t ws_size,
                              hipStream_t stream) {
  const float* hidden = (const float*)d_in[0];
  const float* W_low  = (const float*)d_in[1];
  const float* b_low  = (const float*)d_in[2];
  const float* ln_g   = (const float*)d_in[3];
  const float* ln_b   = (const float*)d_in[4];
  const float* Wq     = (const float*)d_in[5];
  const float* Wk     = (const float*)d_in[6];
  // d_in[7] = Wv, d_in[8] = Wo: dead in forward (output == zq_h exactly)
  const float* cb     = (const float*)d_in[9];
  const float* W_high = (const float*)d_in[10];
  const float* b_high = (const float*)d_in[11];
  float* out = (float*)d_out;
  float* ws  = (float*)d_ws;

  float* ktil = ws + OFF_KTIL;
  float* S    = ws + OFF_S;
  float* csum = ws + OFF_CS;
  float* u    = ws + OFF_U;
  float* tv   = ws + OFF_T;
  float* Mt   = ws + OFF_MT;
  float* ZH   = ws + OFF_ZH;
  int*   flag = (int*)(ws + OFF_FLAG);

  kA1<<<KCL, DCB, 0, stream>>>(cb, Wk, ktil, flag);
  kA2<<<KCL, DCB, 0, stream>>>(Wq, ktil, ln_g, ln_b, b_low, S, csum, tv, u, flag);
  kA3<<<DIN, 128, 0, stream>>>(W_low, S, Mt);
  kA4<<<KCL, 256, 0, stream>>>(cb, W_high, b_high, ZH);
  kB<<<NB / RT, 256, 0, stream>>>(hidden, out, Mt, u, csum, ZH, flag,
                                  S, tv, W_low, b_low);
}

// Round 2
// 540.063 us; speedup vs baseline: 1.1846x; 1.1846x over previous
//
#include <hip/hip_runtime.h>

#define NB    65536   // batch rows
#define DIN   768     // hidden dim
#define DCB   192     // codebook hidden
#define KCL   100     // clusters
#define NJ    112     // padded j (100 scores + col100=mu + pad)
#define RT    128     // rows per block (main kernel)
#define KC    64      // k-chunk

// workspace layout (float offsets)
#define OFF_KTIL 0        // 100*192
#define OFF_S    19200    // 100*192
#define OFF_CS   38400    // 112
#define OFF_U    38512    // 112
#define OFF_T    38624    // 112
#define OFF_MT   38736    // 112*768
#define OFF_ZH   124752   // 100*768
#define OFF_FLAG 201552   // 1 int

// ---------------- setup kernels (small, f64 accumulation, coalesced) ----------------

// ktil[j][i] = sum_m cb[j,m]*Wk[i,m];  also init flag=0
__global__ void kA1(const float* __restrict__ cb, const float* __restrict__ Wk,
                    float* __restrict__ ktil, int* __restrict__ flag) {
  __shared__ float cbrow[DCB];
  int j = blockIdx.x, i = threadIdx.x;  // block=192
  if (j == 0 && i == 0) *flag = 0;
  cbrow[i] = cb[j*DCB + i];
  __syncthreads();
  const float4* wr = (const float4*)&Wk[(size_t)i * DCB];
  double s0 = 0.0, s1 = 0.0;
  #pragma unroll 4
  for (int m4 = 0; m4 < DCB/4; m4++) {
    float4 w = wr[m4];
    s0 += (double)w.x * (double)cbrow[m4*4+0] + (double)w.z * (double)cbrow[m4*4+2];
    s1 += (double)w.y * (double)cbrow[m4*4+1] + (double)w.w * (double)cbrow[m4*4+3];
  }
  ktil[j*DCB+i] = (float)(s0 + s1);
}

// A[j,c] = sum_i Wq[i,c]*ktil[j,i];  S=ln_g*A;  csum[j]=sum_c S;  t[j]=sum_c ln_b*A;
// u[j]=sum_c b_low*S;  u[100]=sum(b_low)/192; pads. flag|=any t!=0.
__global__ void kA2(const float* __restrict__ Wq, const float* __restrict__ ktil,
                    const float* __restrict__ ln_g, const float* __restrict__ ln_b,
                    const float* __restrict__ b_low,
                    float* __restrict__ S, float* __restrict__ csum,
                    float* __restrict__ tv, float* __restrict__ u,
                    int* __restrict__ flag) {
  __shared__ float krow[DCB];
  __shared__ double red[DCB];
  int j = blockIdx.x, c = threadIdx.x;  // block=192
  krow[c] = ktil[j*DCB + c];
  __syncthreads();
  double a0 = 0.0, a1 = 0.0;
  #pragma unroll 4
  for (int i = 0; i < DCB; i += 2) {
    a0 += (double)Wq[i*DCB+c]     * (double)krow[i];
    a1 += (double)Wq[(i+1)*DCB+c] * (double)krow[i+1];
  }
  double a = a0 + a1;
  float Sv = ln_g[c] * (float)a;
  S[j*DCB+c] = Sv;

  red[c] = (double)Sv; __syncthreads();
  if (c == 0) {
    double p0=0,p1=0,p2=0,p3=0;
    for (int i = 0; i < DCB; i += 4) { p0+=red[i]; p1+=red[i+1]; p2+=red[i+2]; p3+=red[i+3]; }
    csum[j] = (float)(p0+p1+p2+p3);
  }
  __syncthreads();
  red[c] = (double)ln_b[c] * a; __syncthreads();
  if (c == 0) {
    double p0=0,p1=0,p2=0,p3=0;
    for (int i = 0; i < DCB; i += 4) { p0+=red[i]; p1+=red[i+1]; p2+=red[i+2]; p3+=red[i+3]; }
    float tf = (float)(p0+p1+p2+p3); tv[j] = tf;
    if (tf != 0.0f) atomicOr(flag, 1);
  }
  __syncthreads();
  red[c] = (double)b_low[c] * (double)Sv; __syncthreads();
  if (c == 0) {
    double p0=0,p1=0,p2=0,p3=0;
    for (int i = 0; i < DCB; i += 4) { p0+=red[i]; p1+=red[i+1]; p2+=red[i+2]; p3+=red[i+3]; }
    u[j] = (float)(p0+p1+p2+p3);
  }
  __syncthreads();
  if (j == 0) {
    red[c] = (double)b_low[c]; __syncthreads();
    if (c == 0) {
      double p0=0,p1=0,p2=0,p3=0;
      for (int i = 0; i < DCB; i += 4) { p0+=red[i]; p1+=red[i+1]; p2+=red[i+2]; p3+=red[i+3]; }
      u[KCL] = (float)((p0+p1+p2+p3) / (double)DCB);
      for (int p = KCL+1; p < NJ; p++) u[p] = 0.f;
      for (int p = KCL;   p < NJ; p++) { csum[p] = 0.f; tv[p] = 0.f; }
    }
  }
}

// Mt[j][d] = sum_c W_low[c,d]*S[j,c]; row 100 = colmean of W_low; pads = 0
// block per j (112 blocks x 256 threads, 3 d per thread) -> coalesced W_low reads
__global__ void kA3(const float* __restrict__ W_low, const float* __restrict__ S,
                    float* __restrict__ Mt) {
  __shared__ float srow[DCB];
  int j = blockIdx.x, t = threadIdx.x;  // block=256
  if (j < KCL && t < DCB) srow[t] = S[j*DCB + t];
  __syncthreads();
  if (j < KCL) {
    double a0 = 0.0, a1 = 0.0, a2 = 0.0;
    for (int c = 0; c < DCB; c++) {
      float sc = srow[c];
      a0 += (double)W_low[(size_t)c*DIN + t]       * (double)sc;
      a1 += (double)W_low[(size_t)c*DIN + t + 256] * (double)sc;
      a2 += (double)W_low[(size_t)c*DIN + t + 512] * (double)sc;
    }
    Mt[(size_t)j*DIN + t]       = (float)a0;
    Mt[(size_t)j*DIN + t + 256] = (float)a1;
    Mt[(size_t)j*DIN + t + 512] = (float)a2;
  } else if (j == KCL) {
    double a0 = 0.0, a1 = 0.0, a2 = 0.0;
    for (int c = 0; c < DCB; c++) {
      a0 += (double)W_low[(size_t)c*DIN + t];
      a1 += (double)W_low[(size_t)c*DIN + t + 256];
      a2 += (double)W_low[(size_t)c*DIN + t + 512];
    }
    Mt[(size_t)j*DIN + t]       = (float)(a0 / (double)DCB);
    Mt[(size_t)j*DIN + t + 256] = (float)(a1 / (double)DCB);
    Mt[(size_t)j*DIN + t + 512] = (float)(a2 / (double)DCB);
  } else {
    Mt[(size_t)j*DIN + t]       = 0.f;
    Mt[(size_t)j*DIN + t + 256] = 0.f;
    Mt[(size_t)j*DIN + t + 512] = 0.f;
  }
}

// ZH[j][d] = sum_c cb[j,c]*W_high[d,c] + b_high[d]
__global__ void kA4(const float* __restrict__ cb, const float* __restrict__ W_high,
                    const float* __restrict__ b_high, float* __restrict__ ZH) {
  __shared__ float cbrow[DCB];
  int j = blockIdx.x, t = threadIdx.x;  // block=256
  if (t < DCB) cbrow[t] = cb[j*DCB + t];
  __syncthreads();
  #pragma unroll
  for (int kd = 0; kd < 3; kd++) {
    int d = t + 256*kd;
    const float4* wr = (const float4*)&W_high[(size_t)d * DCB];
    double s0 = 0.0, s1 = 0.0;
    #pragma unroll 4
    for (int c4 = 0; c4 < DCB/4; c4++) {
      float4 w = wr[c4];
      s0 += (double)w.x * (double)cbrow[c4*4+0] + (double)w.z * (double)cbrow[c4*4+2];
      s1 += (double)w.y * (double)cbrow[c4*4+1] + (double)w.w * (double)cbrow[c4*4+3];
    }
    ZH[(size_t)j*DIN + d] = (float)(s0 + s1 + (double)b_high[d]);
  }
}

// ---------------- main kernel ----------------
// 256 threads: jg = tid&15 (7 j each), rg = tid>>4 (8 rows each) -> 128 rows x 112 j
__global__ __launch_bounds__(256, 2)
void kB(const float* __restrict__ hidden, float* __restrict__ out,
        const float* __restrict__ Mt, const float* __restrict__ u,
        const float* __restrict__ csum, const float* __restrict__ ZH,
        const int* __restrict__ flag,
        const float* __restrict__ S, const float* __restrict__ tv,
        const float* __restrict__ W_low, const float* __restrict__ b_low) {
  __shared__ float hs[RT * 68];    // 128 rows x 64 k, stride 68  (34816 B)
  __shared__ float Ms[NJ * 68];    // 112 j   x 64 k, stride 68  (30464 B)
  __shared__ float uc[NJ];
  __shared__ float cs[NJ];
  __shared__ int   idxs[RT];
  const int tid = threadIdx.x;
  const int r0  = blockIdx.x * RT;

  if (*flag == 0) {
    // ---- fast path: ln_b == 0 -> t == 0, argmax invariant to the LN scale r ----
    const int jg = tid & 15, rg = tid >> 4;
    const int jbase = jg * 7, rbase = rg * 8;
    const int lane = tid & 63;
    const int grpbase = lane & ~15;   // 16-lane group sharing the same rows
    if (tid < NJ) { uc[tid] = u[tid]; cs[tid] = csum[tid]; }

    float acc[8][7];
    #pragma unroll
    for (int i = 0; i < 8; i++)
      #pragma unroll
      for (int j = 0; j < 7; j++) acc[i][j] = 0.f;

    for (int ck = 0; ck < DIN / KC; ck++) {
      const int k0 = ck * KC;
      __syncthreads();
      #pragma unroll
      for (int i = 0; i < 8; i++) {            // hidden tile: 2048 float4
        int f = tid + 256 * i;
        int r = f >> 4, k4 = f & 15;
        float4 v = *(const float4*)&hidden[(size_t)(r0 + r) * DIN + k0 + k4 * 4];
        *(float4*)&hs[r * 68 + k4 * 4] = v;
      }
      #pragma unroll
      for (int i = 0; i < 7; i++) {            // Mt tile: 1792 float4
        int f = tid + 256 * i;
        int j = f >> 4, k4 = f & 15;
        float4 v = *(const float4*)&Mt[(size_t)j * DIN + k0 + k4 * 4];
        *(float4*)&Ms[j * 68 + k4 * 4] = v;
      }
      __syncthreads();
      #pragma unroll 4
      for (int kk = 0; kk < KC; kk += 4) {
        float4 h4[8], m4[7];
        #pragma unroll
        for (int j = 0; j < 7; j++) m4[j] = *(const float4*)&Ms[(jbase + j) * 68 + kk];
        #pragma unroll
        for (int i = 0; i < 8; i++) h4[i] = *(const float4*)&hs[(rbase + i) * 68 + kk];
        #pragma unroll
        for (int i = 0; i < 8; i++)
          #pragma unroll
          for (int j = 0; j < 7; j++) {
            acc[i][j] += h4[i].x * m4[j].x;
            acc[i][j] += h4[i].y * m4[j].y;
            acc[i][j] += h4[i].z * m4[j].z;
            acc[i][j] += h4[i].w * m4[j].w;
          }
      }
    }
    // ---- argmax via shfl: the 16 lanes grpbase..grpbase+15 share rows rbase..rbase+7 ----
    const float u100 = uc[KCL];
    #pragma unroll
    for (int i = 0; i < 8; i++) {
      // mu = G[row][100]: held by jg==14 as acc[i][2] (j = 98+2)
      float mu = __shfl(acc[i][2], grpbase + 14, 64) + u100;
      float lb = -3.4e38f; int li = 0;
      #pragma unroll
      for (int j = 0; j < 7; j++) {
        int jj = jbase + j;
        float s = acc[i][j] + uc[jj] - mu * cs[jj];
        s = (jj < KCL) ? s : -3.4e38f;
        if (s > lb) { lb = s; li = jj; }   // strict > : first max == np's first argmin of attn_w
      }
      #pragma unroll
      for (int off = 1; off < 16; off <<= 1) {
        float ov = __shfl_xor(lb, off, 64);
        int   oi = __shfl_xor(li, off, 64);
        if (ov > lb || (ov == lb && oi < li)) { lb = ov; li = oi; }
      }
      if (jg == 0) idxs[rbase + i] = li;
    }
    __syncthreads();
    for (int i = 0; i < 96; i++) {            // copy ZH[idx] rows: 24576 float4
      int f = tid + 256 * i;
      int r = f / 192, d4 = f - r * 192;
      int idx = idxs[r];
      float4 v = *(const float4*)&ZH[(size_t)idx * DIN + d4 * 4];
      *(float4*)&out[(size_t)(r0 + r) * DIN + d4 * 4] = v;
    }
  } else {
    // ---- general (slow) path: ln_b != 0 -> full pat + LayerNorm. Correctness only. ----
    float* hrow = hs;          // 768
    float* patv = hs + 768;    // 192
    float* redf = hs + 960;    // 2
    float* Gsc  = Ms;          // 100 scores
    for (int rr = 0; rr < RT; rr++) {
      const size_t row = (size_t)(r0 + rr);
      __syncthreads();
      for (int d = tid; d < DIN; d += 256) hrow[d] = hidden[row * DIN + d];
      __syncthreads();
      if (tid < DCB) {
        float a = b_low[tid];
        for (int d = 0; d < DIN; d++) a += hrow[d] * W_low[(size_t)tid * DIN + d];
        patv[tid] = a;
      }
      __syncthreads();
      if (tid == 0) {
        float mu = 0.f; for (int c = 0; c < DCB; c++) mu += patv[c]; mu /= (float)DCB;
        float var = 0.f; for (int c = 0; c < DCB; c++) { float dd = patv[c] - mu; var += dd * dd; }
        var /= (float)DCB;
        redf[0] = mu; redf[1] = rsqrtf(var + 1e-5f);
      }
      __syncthreads();
      if (tid < DCB) patv[tid] = (patv[tid] - redf[0]) * redf[1];
      __syncthreads();
      if (tid < KCL) {
        float s = tv[tid];
        for (int c = 0; c < DCB; c++) s += patv[c] * S[(size_t)tid * DCB + c];
        Gsc[tid] = s;
      }
      __syncthreads();
      if (tid == 0) {
        float best = -3.4e38f; int bi = 0;
        for (int j = 0; j < KCL; j++) if (Gsc[j] > best) { best = Gsc[j]; bi = j; }
        idxs[0] = bi;
      }
      __syncthreads();
      {
        int idx = idxs[0];
        for (int d4 = tid; d4 < DIN / 4; d4 += 256) {
          float4 v = *(const float4*)&ZH[(size_t)idx * DIN + d4 * 4];
          *(float4*)&out[row * DIN + d4 * 4] = v;
        }
      }
    }
  }
}

extern "C" void kernel_launch(void* const* d_in, const int* in_sizes, int n_in,
                              void* d_out, int out_size, void* d_ws, size_t ws_size,
                              hipStream_t stream) {
  const float* hidden = (const float*)d_in[0];
  const float* W_low  = (const float*)d_in[1];
  const float* b_low  = (const float*)d_in[2];
  const float* ln_g   = (const float*)d_in[3];
  const float* ln_b   = (const float*)d_in[4];
  const float* Wq     = (const float*)d_in[5];
  const float* Wk     = (const float*)d_in[6];
  // d_in[7] = Wv, d_in[8] = Wo: dead in forward (output == zq_h exactly)
  const float* cb     = (const float*)d_in[9];
  const float* W_high = (const float*)d_in[10];
  const float* b_high = (const float*)d_in[11];
  float* out = (float*)d_out;
  float* ws  = (float*)d_ws;

  float* ktil = ws + OFF_KTIL;
  float* S    = ws + OFF_S;
  float* csum = ws + OFF_CS;
  float* u    = ws + OFF_U;
  float* tv   = ws + OFF_T;
  float* Mt   = ws + OFF_MT;
  float* ZH   = ws + OFF_ZH;
  int*   flag = (int*)(ws + OFF_FLAG);

  kA1<<<KCL, DCB, 0, stream>>>(cb, Wk, ktil, flag);
  kA2<<<KCL, DCB, 0, stream>>>(Wq, ktil, ln_g, ln_b, b_low, S, csum, tv, u, flag);
  kA3<<<NJ,  256, 0, stream>>>(W_low, S, Mt);
  kA4<<<KCL, 256, 0, stream>>>(cb, W_high, b_high, ZH);
  kB<<<NB / RT, 256, 0, stream>>>(hidden, out, Mt, u, csum, ZH, flag,
                                  S, tv, W_low, b_low);
}